// Round 1
// baseline (222.072 us; speedup 1.0000x reference)
//
#include <hip/hip_runtime.h>
#include <math.h>

// Problem constants
#define NB 8      // batch
#define NC 256    // channels
#define NN 1024   // spatial H*W
#define NICH 64   // inter channels

// ws layout (float offsets)
#define WS_AQ   0        // [256]
#define WS_AK   256      // [256]
#define WS_CQ   512
#define WS_CK   513
#define WS_GE   514      // gamma_eff
#define WS_STAT 1024     // per-batch stats, stride 4096
#define STAT_STRIDE 4096
#define ST_EQ   0        // [1024]
#define ST_EK   1024     // [1024]
#define ST_SV   2048     // [256]
#define ST_SVE  2304     // [256]
#define WS_NX2  34816    // [8]
#define WS_ND2  34824    // [8]
#define WS_TR   34832    // [8]
#define WS_SB   34840    // [8]
#define WS_P    35072    // [8][256]
#define WS_R    37120    // [8][256]
#define WS_VSP  40960    // [8][16][256]
#define WS_VEP  73728    // [8][16][256]
#define WS_DOTP 106496   // [8][16]
#define WS_V    131072   // [8*256*1024] v buffer

// K0: aq = Wq^T Wc[:64], ak = Wk^T Wc[64:], cq = Wc[:64]*bq, ck = Wc[64:]*bk
__global__ void kprep(const float* __restrict__ Wq, const float* __restrict__ bq,
                      const float* __restrict__ Wk, const float* __restrict__ bk,
                      const float* __restrict__ Wc, float* __restrict__ ws) {
    int t = threadIdx.x;  // 256
    float a = 0.f, k = 0.f;
    for (int o = 0; o < NICH; ++o) {
        a += Wc[o] * Wq[o * NC + t];
        k += Wc[NICH + o] * Wk[o * NC + t];
    }
    ws[WS_AQ + t] = a;
    ws[WS_AK + t] = k;
    __shared__ float red[64];
    if (t < 64) red[t] = Wc[t] * bq[t];
    __syncthreads();
    if (t == 0) { float s = 0.f; for (int i = 0; i < 64; ++i) s += red[i]; ws[WS_CQ] = s; }
    __syncthreads();
    if (t < 64) red[t] = Wc[NICH + t] * bk[t];
    __syncthreads();
    if (t == 0) { float s = 0.f; for (int i = 0; i < 64; ++i) s += red[i]; ws[WS_CK] = s; }
}

// K1: per-batch stats eq,ek,sx,xe,Seq,Sv,Sve + analytic lip norm partials
__global__ void kstats(const float* __restrict__ x, const float* __restrict__ Wv,
                       const float* __restrict__ bv, const float* __restrict__ gamma,
                       float* __restrict__ ws) {
    const int b = blockIdx.x, t = threadIdx.x;  // 8 blocks x 1024 threads
    __shared__ float aql[NC], akl[NC], eql[NN], ekl[NN];
    __shared__ float sxl[NC], xel[NC], Svl[NC], Al[NC], SvLl[NC];
    __shared__ float redA[1024], redB[1024];
    __shared__ float Seqs;
    if (t < NC) { aql[t] = ws[WS_AQ + t]; akl[t] = ws[WS_AK + t]; }
    __syncthreads();
    const float cq = ws[WS_CQ], ck = ws[WS_CK];
    const float* xb = x + (size_t)b * NC * NN;
    // phase a: eq/ek (thread = spatial position)
    float ea = 0.f, eb = 0.f;
    for (int c = 0; c < NC; ++c) {
        float xv = xb[c * NN + t];
        ea += aql[c] * xv;
        eb += akl[c] * xv;
    }
    float eqv = ea + cq, ekv = eb + ck;
    eql[t] = eqv; ekl[t] = ekv;
    float* st = ws + WS_STAT + b * STAT_STRIDE;
    st[ST_EQ + t] = eqv;
    st[ST_EK + t] = ekv;
    __syncthreads();
    // Seq
    redA[t] = eqv;
    __syncthreads();
    for (int s = 512; s > 0; s >>= 1) { if (t < s) redA[t] += redA[t + s]; __syncthreads(); }
    if (t == 0) Seqs = redA[0];
    __syncthreads();
    const float Seq = Seqs;
    // phase b: sx, xe (thread = (c, quarter-of-n))
    {
        int c = t >> 2, sub = t & 3;
        float sxa = 0.f, xea = 0.f;
        const float* xr = xb + c * NN + sub * 256;
        for (int i = 0; i < 256; ++i) { float xv = xr[i]; sxa += xv; xea += xv * eql[sub * 256 + i]; }
        redA[t] = sxa; redB[t] = xea;
        __syncthreads();
        if (sub == 0) {
            sxl[c] = redA[t] + redA[t + 1] + redA[t + 2] + redA[t + 3];
            xel[c] = redB[t] + redB[t + 1] + redB[t + 2] + redB[t + 3];
        }
        __syncthreads();
    }
    // phase c: Sv, Sve, A, SvL
    {
        int c = t >> 2, sub = t & 3;
        float sva = 0.f, svea = 0.f;
        const float* wr = Wv + c * NC + sub * 64;
        for (int i = 0; i < 64; ++i) {
            float w = wr[i]; int ci = sub * 64 + i;
            sva += w * sxl[ci]; svea += w * xel[ci];
        }
        redA[t] = sva; redB[t] = svea;
        __syncthreads();
        if (sub == 0) {
            float Wsx = redA[t] + redA[t + 1] + redA[t + 2] + redA[t + 3];
            float Wxe = redB[t] + redB[t + 1] + redB[t + 2] + redB[t + 3];
            float Sv  = Wsx + (float)NN * bv[c];
            float Sve = Wxe + bv[c] * Seq;
            Svl[c] = Sv; SvLl[c] = Wsx;
            Al[c] = 2.f * Sve - bv[c] * Seq - cq * Sv;   // dSve (analytic)
            st[ST_SV + c] = Sv; st[ST_SVE + c] = Sve;
        }
        __syncthreads();
    }
    // phase d: analytic lip norm partials (D = directional derivative along x)
    {
        const float g0 = gamma[0];
        const float inv = g0 * (1.f / (float)NN);
        float d2 = 0.f, x2 = 0.f;
        float ekc = ekl[t];
        float ekL = ekc - ck;
        for (int c = 0; c < NC; ++c) {
            float xv = xb[c * NN + t];
            float D = xv + inv * (Al[c] + ekL * Svl[c] + ekc * SvLl[c]);
            d2 += D * D; x2 += xv * xv;
        }
        redA[t] = d2; redB[t] = x2;
        __syncthreads();
        for (int s = 512; s > 0; s >>= 1) {
            if (t < s) { redA[t] += redA[t + s]; redB[t] += redB[t + s]; }
            __syncthreads();
        }
        if (t == 0) { ws[WS_ND2 + b] = redA[0]; ws[WS_NX2 + b] = redB[0]; }
    }
}

// K2: lip -> gamma_eff
__global__ void klip(const float* __restrict__ gamma, float* __restrict__ ws) {
    if (threadIdx.x == 0) {
        float d2 = 0.f, x2 = 0.f;
        for (int b = 0; b < NB; ++b) { d2 += ws[WS_ND2 + b]; x2 += ws[WS_NX2 + b]; }
        float lip = sqrtf(d2 / x2);
        float factor = (lip > 0.9f) ? (0.9f / lip) : 1.0f;
        ws[WS_GE] = gamma[0] * factor;
    }
}

// Output 0: x + Fx = 2x + (ge/N)(Sve[c] + ek[m]*Sv[c])
__global__ void kout0(const float* __restrict__ x, const float* __restrict__ ws,
                      float* __restrict__ out) {
    int bid = blockIdx.x;            // b*256 + c
    int b = bid >> 8, c = bid & 255, m = threadIdx.x;
    const float* st = ws + WS_STAT + b * STAT_STRIDE;
    float ge = ws[WS_GE] * (1.f / (float)NN);
    float sv = st[ST_SV + c], sve = st[ST_SVE + c];
    float ekv = st[ST_EK + m];
    size_t idx = (size_t)bid * NN + m;
    out[idx] = 2.f * x[idx] + ge * (sve + ekv * sv);
}

// Reduce Vs/Ve partials of u (v_0)
__global__ void kredu(const float* __restrict__ u, float* __restrict__ ws) {
    int bid = blockIdx.x;            // 128 blocks: b*16 + chunk
    int b = bid >> 4, ch = bid & 15;
    int t = threadIdx.x;             // 1024
    int col = t & 63, q = t >> 6;    // 64 cols, 16 c-groups
    int nb = ch * 64;
    __shared__ float ekc[64];
    __shared__ float VsPl[NC], VePl[NC];
    if (t < 64) ekc[t] = ws[WS_STAT + b * STAT_STRIDE + ST_EK + nb + t];
    __syncthreads();
    const float* ub = u + (size_t)b * NC * NN + nb + col;
    float ekv = ekc[col];
    for (int i = 0; i < 16; ++i) {
        int c = q * 16 + i;
        float uv = ub[(size_t)c * NN];
        float s1 = uv, s2 = uv * ekv;
        for (int off = 32; off > 0; off >>= 1) {
            s1 += __shfl_down(s1, off, 64);
            s2 += __shfl_down(s2, off, 64);
        }
        if (col == 0) { VsPl[c] = s1; VePl[c] = s2; }
    }
    __syncthreads();
    if (t < NC) {
        ws[WS_VSP + (b * 16 + ch) * NC + t] = VsPl[t];
        ws[WS_VEP + (b * 16 + ch) * NC + t] = VePl[t];
    }
}

// Finalize Vs/Ve -> p, r, sB; accumulate trace term
__global__ void ktiny(const float* __restrict__ Wv, const float* __restrict__ bv,
                      float* __restrict__ ws, float* __restrict__ out,
                      int j, float coef) {
    int b = blockIdx.x, t = threadIdx.x;  // 8 blocks x 256
    __shared__ float Vsl[NC], Vel[NC], red[NC];
    float vs = 0.f, ve = 0.f;
    for (int k = 0; k < 16; ++k) {
        vs += ws[WS_VSP + (b * 16 + k) * NC + t];
        ve += ws[WS_VEP + (b * 16 + k) * NC + t];
    }
    Vsl[t] = vs; Vel[t] = ve;
    __syncthreads();
    float pa = 0.f, ra = 0.f;
    for (int c = 0; c < NC; ++c) {
        float w = Wv[c * NC + t];
        pa += w * Vsl[c];
        ra += w * Vel[c];
    }
    float s = ws[WS_GE] * (1.f / (float)NN);
    ws[WS_P + b * NC + t] = s * pa;
    ws[WS_R + b * NC + t] = s * ra;
    red[t] = bv[t] * Vsl[t];
    __syncthreads();
    for (int sh = 128; sh > 0; sh >>= 1) { if (t < sh) red[t] += red[t + sh]; __syncthreads(); }
    if (t == 0) {
        ws[WS_SB + b] = s * red[0];
        if (j == 0) {
            ws[WS_TR + b] = 0.f;
        } else {
            float dot = 0.f;
            for (int k = 0; k < 16; ++k) dot += ws[WS_DOTP + b * 16 + k];
            float trv = ws[WS_TR + b] + coef * dot;
            ws[WS_TR + b] = trv;
            if (j == 5) out[(size_t)NB * NC * NN / NB * NB + b] = trv;  // 2097152 + b
        }
    }
}

// One vjp application: w = v + p*eq + aq*(pz+sB) + ak*t + r ; fused next reductions + dot
__global__ void kupd(const float* __restrict__ x, const float* __restrict__ u,
                     float* __restrict__ ws, const float* __restrict__ src,
                     float* __restrict__ dst) {
    int bid = blockIdx.x;            // 128 blocks: b*16 + chunk
    int b = bid >> 4, ch = bid & 15;
    int t = threadIdx.x;             // 1024
    int col = t & 63, q = t >> 6;
    int nb = ch * 64;
    __shared__ float pl[NC], rl[NC], aql[NC], akl[NC], Svl[NC];
    __shared__ float redA[1024], redB[1024];
    __shared__ float tl[64], pzl[64];
    __shared__ float VsPl[NC], VePl[NC];
    const float* st = ws + WS_STAT + b * STAT_STRIDE;
    if (t < NC) {
        pl[t] = ws[WS_P + b * NC + t];
        rl[t] = ws[WS_R + b * NC + t];
        aql[t] = ws[WS_AQ + t];
        akl[t] = ws[WS_AK + t];
        Svl[t] = st[ST_SV + t];
    }
    __syncthreads();
    const float sB = ws[WS_SB + b];
    const float s = ws[WS_GE] * (1.f / (float)NN);
    const float* vb = src + (size_t)b * NC * NN + nb + col;
    const float* xb = x + (size_t)b * NC * NN + nb + col;
    float vreg[16];
    float ta = 0.f, pza = 0.f;
    for (int i = 0; i < 16; ++i) {
        int c = q * 16 + i;
        float vv = vb[(size_t)c * NN];
        vreg[i] = vv;
        ta += vv * Svl[c];
        pza += xb[(size_t)c * NN] * pl[c];
    }
    redA[t] = ta; redB[t] = pza;
    __syncthreads();
    if (t < 64) {
        float tv = 0.f, pv = 0.f;
        for (int qq = 0; qq < 16; ++qq) { tv += redA[qq * 64 + t]; pv += redB[qq * 64 + t]; }
        tl[t] = s * tv;   // t[p] = (g/N) * sum_c v[c,p]*Sv[c]
        pzl[t] = pv;      // pz already carries (g/N) through p
    }
    __syncthreads();
    const float eqv = st[ST_EQ + nb + col];
    const float ekv = st[ST_EK + nb + col];
    const float tv = tl[col];
    const float pzv = pzl[col] + sB;
    float* db = dst + (size_t)b * NC * NN + nb + col;
    const float* ub = u + (size_t)b * NC * NN + nb + col;
    float dot = 0.f;
    for (int i = 0; i < 16; ++i) {
        int c = q * 16 + i;
        float w = vreg[i] + pl[c] * eqv + aql[c] * pzv + akl[c] * tv + rl[c];
        db[(size_t)c * NN] = w;
        dot += w * ub[(size_t)c * NN];
        float s1 = w, s2 = w * ekv;
        for (int off = 32; off > 0; off >>= 1) {
            s1 += __shfl_down(s1, off, 64);
            s2 += __shfl_down(s2, off, 64);
        }
        if (col == 0) { VsPl[c] = s1; VePl[c] = s2; }
    }
    redA[t] = dot;
    __syncthreads();
    for (int sh = 512; sh > 0; sh >>= 1) { if (t < sh) redA[t] += redA[t + sh]; __syncthreads(); }
    if (t == 0) ws[WS_DOTP + b * 16 + ch] = redA[0];
    if (t < NC) {
        ws[WS_VSP + (b * 16 + ch) * NC + t] = VsPl[t];
        ws[WS_VEP + (b * 16 + ch) * NC + t] = VePl[t];
    }
}

extern "C" void kernel_launch(void* const* d_in, const int* in_sizes, int n_in,
                              void* d_out, int out_size, void* d_ws, size_t ws_size,
                              hipStream_t stream) {
    const float* x     = (const float*)d_in[0];
    const float* Wq    = (const float*)d_in[1];
    const float* bq    = (const float*)d_in[2];
    const float* Wk    = (const float*)d_in[3];
    const float* bk    = (const float*)d_in[4];
    const float* Wc    = (const float*)d_in[5];
    const float* Wv    = (const float*)d_in[6];
    const float* bv    = (const float*)d_in[7];
    const float* gamma = (const float*)d_in[8];
    const float* u     = (const float*)d_in[9];
    float* out = (float*)d_out;
    float* ws  = (float*)d_ws;
    float* V   = ws + WS_V;

    kprep<<<dim3(1), dim3(256), 0, stream>>>(Wq, bq, Wk, bk, Wc, ws);
    kstats<<<dim3(NB), dim3(1024), 0, stream>>>(x, Wv, bv, gamma, ws);
    klip<<<dim3(1), dim3(64), 0, stream>>>(gamma, ws);
    kout0<<<dim3(NB * NC), dim3(NN), 0, stream>>>(x, ws, out);
    kredu<<<dim3(128), dim3(1024), 0, stream>>>(u, ws);

    const float coefs[6] = {0.f, 1.f, -0.5f, 1.f / 3.f, -0.25f, 0.2f};
    ktiny<<<dim3(NB), dim3(256), 0, stream>>>(Wv, bv, ws, out, 0, 0.f);
    for (int j = 1; j <= 5; ++j) {
        const float* src = (j == 1) ? u : (const float*)V;
        kupd<<<dim3(128), dim3(1024), 0, stream>>>(x, u, ws, src, V);
        ktiny<<<dim3(NB), dim3(256), 0, stream>>>(Wv, bv, ws, out, j, coefs[j]);
    }
}

// Round 2
// 196.366 us; speedup vs baseline: 1.1309x; 1.1309x over previous
//
#include <hip/hip_runtime.h>
#include <math.h>

// Problem constants
#define NB 8      // batch
#define NC 256    // channels
#define NN 1024   // spatial H*W
#define NICH 64   // inter channels

// ws layout (float offsets)
#define WS_AQ   0        // [256]
#define WS_AK   256      // [256]
#define WS_CQ   512
#define WS_CK   513
#define WS_GE   514
#define WS_MOM  520      // [8][4][3] Seq/Sek/Sek2 chunk partials
#define WS_SX   1024     // [8][256]
#define WS_XE   3072     // [8][256]
#define WS_XK   5120     // [8][256]
#define WS_SX2P 7168     // [8][16]
#define WS_NX2  7296     // [8]
#define WS_ND2  7304     // [8]
#define WS_TR   7312     // [8]
#define WS_SB   7320     // [8]
#define WS_P    7424     // [8][256]
#define WS_R    9472     // [8][256]
#define WS_STAT 11520    // [8] stride 2560
#define STAT_STRIDE 2560
#define ST_EQ   0        // [1024]
#define ST_EK   1024     // [1024]
#define ST_SV   2048     // [256]
#define ST_SVE  2304     // [256]
#define WS_EQP  32768    // [128][1024] (dead after k2)
#define WS_EKP  163840   // [128][1024] (dead after k2)
#define WS_VSP  32768    // [8][32][256] overlaps dead EQP
#define WS_VEP  98304    // [8][32][256]
#define WS_DOTP 163840   // [8][32] overlaps dead EKP
#define WS_V    164096   // [2097152] v buffer

// k1: per (b, 16-channel group): eq/ek partials over all n, exact sx per channel.
// Also computes aq/ak (for its channels) and cq/ck, folding in old kprep.
__global__ void k1(const float* __restrict__ x, const float* __restrict__ Wq,
                   const float* __restrict__ bq, const float* __restrict__ Wk,
                   const float* __restrict__ bk, const float* __restrict__ Wc,
                   float* __restrict__ ws) {
    const int bid = blockIdx.x;          // 128: b*16+g
    const int b = bid >> 4, g = bid & 15;
    const int t = threadIdx.x;           // 256
    const int c0 = g * 16;
    __shared__ float aql[16], akl[16];
    __shared__ float sxw[16][4];
    if (t < 16) {
        float a = 0.f, k = 0.f;
        for (int o = 0; o < NICH; ++o) {
            a += Wc[o] * Wq[o * NC + c0 + t];
            k += Wc[NICH + o] * Wk[o * NC + c0 + t];
        }
        aql[t] = a; akl[t] = k;
        ws[WS_AQ + c0 + t] = a;
        ws[WS_AK + c0 + t] = k;
    }
    if (t == 16) { float s = 0.f; for (int o = 0; o < 64; ++o) s += Wc[o] * bq[o]; ws[WS_CQ] = s; }
    if (t == 17) { float s = 0.f; for (int o = 0; o < 64; ++o) s += Wc[NICH + o] * bk[o]; ws[WS_CK] = s; }
    __syncthreads();
    const float* xb = x + ((size_t)b * NC + c0) * NN;
    float eqp0 = 0.f, eqp1 = 0.f, eqp2 = 0.f, eqp3 = 0.f;
    float ekp0 = 0.f, ekp1 = 0.f, ekp2 = 0.f, ekp3 = 0.f;
    const int wid = t >> 6, lane = t & 63;
    for (int c = 0; c < 16; ++c) {
        float x0 = xb[c * NN + t];
        float x1 = xb[c * NN + t + 256];
        float x2 = xb[c * NN + t + 512];
        float x3 = xb[c * NN + t + 768];
        float a = aql[c], k = akl[c];
        eqp0 += a * x0; eqp1 += a * x1; eqp2 += a * x2; eqp3 += a * x3;
        ekp0 += k * x0; ekp1 += k * x1; ekp2 += k * x2; ekp3 += k * x3;
        float s = x0 + x1 + x2 + x3;
        for (int off = 32; off > 0; off >>= 1) s += __shfl_down(s, off, 64);
        if (lane == 0) sxw[c][wid] = s;
    }
    __syncthreads();
    if (t < 16) ws[WS_SX + b * NC + c0 + t] = sxw[t][0] + sxw[t][1] + sxw[t][2] + sxw[t][3];
    size_t pb = (size_t)bid * 1024;
    ws[WS_EQP + pb + t]       = eqp0;
    ws[WS_EQP + pb + t + 256] = eqp1;
    ws[WS_EQP + pb + t + 512] = eqp2;
    ws[WS_EQP + pb + t + 768] = eqp3;
    ws[WS_EKP + pb + t]       = ekp0;
    ws[WS_EKP + pb + t + 256] = ekp1;
    ws[WS_EKP + pb + t + 512] = ekp2;
    ws[WS_EKP + pb + t + 768] = ekp3;
}

// k2: finalize eq/ek, compute chunk moments Seq/Sek/Sek2
__global__ void k2(float* __restrict__ ws) {
    const int bid = blockIdx.x;      // 32: b*4+qc
    const int b = bid >> 2, qc = bid & 3;
    const int t = threadIdx.x;       // 256
    const int n = qc * 256 + t;
    const float cq = ws[WS_CQ], ck = ws[WS_CK];
    float e = 0.f, k = 0.f;
    for (int g = 0; g < 16; ++g) {
        size_t pb = (size_t)(b * 16 + g) * 1024 + n;
        e += ws[WS_EQP + pb];
        k += ws[WS_EKP + pb];
    }
    e += cq; k += ck;
    float* st = ws + WS_STAT + b * STAT_STRIDE;
    st[ST_EQ + n] = e;
    st[ST_EK + n] = k;
    __shared__ float red[256];
    red[t] = e; __syncthreads();
    for (int s = 128; s > 0; s >>= 1) { if (t < s) red[t] += red[t + s]; __syncthreads(); }
    if (t == 0) ws[WS_MOM + bid * 3 + 0] = red[0];
    __syncthreads();
    red[t] = k; __syncthreads();
    for (int s = 128; s > 0; s >>= 1) { if (t < s) red[t] += red[t + s]; __syncthreads(); }
    if (t == 0) ws[WS_MOM + bid * 3 + 1] = red[0];
    __syncthreads();
    red[t] = k * k; __syncthreads();
    for (int s = 128; s > 0; s >>= 1) { if (t < s) red[t] += red[t + s]; __syncthreads(); }
    if (t == 0) ws[WS_MOM + bid * 3 + 2] = red[0];
}

// k3: per-channel xe = sum x*eq, xk = sum x*ek, plus x^2 partials
__global__ void k3(const float* __restrict__ x, float* __restrict__ ws) {
    const int bid = blockIdx.x;   // 128: b*16+g
    const int b = bid >> 4, g = bid & 15;
    const int t = threadIdx.x;    // 256
    const int c0 = g * 16;
    __shared__ float eql[NN], ekl[NN];
    __shared__ float xew[16][4], xkw[16][4];
    __shared__ float x2w[4];
    const float* st = ws + WS_STAT + b * STAT_STRIDE;
    for (int j = 0; j < 4; ++j) {
        eql[t + 256 * j] = st[ST_EQ + t + 256 * j];
        ekl[t + 256 * j] = st[ST_EK + t + 256 * j];
    }
    __syncthreads();
    const float* xb = x + ((size_t)b * NC + c0) * NN;
    float x2a = 0.f;
    const int wid = t >> 6, lane = t & 63;
    for (int c = 0; c < 16; ++c) {
        float xe = 0.f, xk = 0.f;
        for (int j = 0; j < 4; ++j) {
            float xv = xb[c * NN + t + 256 * j];
            xe += xv * eql[t + 256 * j];
            xk += xv * ekl[t + 256 * j];
            x2a += xv * xv;
        }
        for (int off = 32; off > 0; off >>= 1) {
            xe += __shfl_down(xe, off, 64);
            xk += __shfl_down(xk, off, 64);
        }
        if (lane == 0) { xew[c][wid] = xe; xkw[c][wid] = xk; }
    }
    for (int off = 32; off > 0; off >>= 1) x2a += __shfl_down(x2a, off, 64);
    if (lane == 0) x2w[wid] = x2a;
    __syncthreads();
    if (t < 16) {
        ws[WS_XE + b * NC + c0 + t] = xew[t][0] + xew[t][1] + xew[t][2] + xew[t][3];
        ws[WS_XK + b * NC + c0 + t] = xkw[t][0] + xkw[t][1] + xkw[t][2] + xkw[t][3];
    }
    if (t == 0) ws[WS_SX2P + bid] = x2w[0] + x2w[1] + x2w[2] + x2w[3];
}

// k4: Sv/Sve/A + algebraic d2 (no third pass over x)
__global__ void k4(const float* __restrict__ Wv, const float* __restrict__ bv,
                   const float* __restrict__ gamma, float* __restrict__ ws) {
    const int b = blockIdx.x, t = threadIdx.x;  // 8 x 256
    __shared__ float sxl[NC], xel[NC];
    __shared__ float redA[256], redB[256];
    sxl[t] = ws[WS_SX + b * NC + t];
    xel[t] = ws[WS_XE + b * NC + t];
    __syncthreads();
    float Wsx = 0.f, Wxe = 0.f;
    const float* wr = Wv + (size_t)t * NC;
    for (int k = 0; k < NC; ++k) { float w = wr[k]; Wsx += w * sxl[k]; Wxe += w * xel[k]; }
    float Seq = 0.f, Sek = 0.f, Sek2 = 0.f;
    for (int q = 0; q < 4; ++q) {
        Seq  += ws[WS_MOM + (b * 4 + q) * 3 + 0];
        Sek  += ws[WS_MOM + (b * 4 + q) * 3 + 1];
        Sek2 += ws[WS_MOM + (b * 4 + q) * 3 + 2];
    }
    const float cq = ws[WS_CQ], ck = ws[WS_CK];
    float bvc = bv[t];
    float Sv  = Wsx + (float)NN * bvc;
    float SvL = Wsx;
    float Sve = Wxe + bvc * Seq;
    float A   = 2.f * Sve - bvc * Seq - cq * Sv;
    float* st = ws + WS_STAT + b * STAT_STRIDE;
    st[ST_SV + t] = Sv; st[ST_SVE + t] = Sve;
    float sx = sxl[t];
    float xk = ws[WS_XK + b * NC + t];
    float xkL = xk - ck * sx;
    float T1c = A * sx + Sv * xkL + SvL * xk;
    float SP  = Sek - (float)NN * ck;
    float SP2 = Sek2 - 2.f * ck * Sek + (float)NN * ck * ck;
    float SPQ = Sek2 - ck * Sek;
    float T2c = (float)NN * A * A + Sv * Sv * SP2 + SvL * SvL * Sek2
              + 2.f * A * Sv * SP + 2.f * A * SvL * Sek + 2.f * Sv * SvL * SPQ;
    redA[t] = T1c; redB[t] = T2c;
    __syncthreads();
    for (int s = 128; s > 0; s >>= 1) {
        if (t < s) { redA[t] += redA[t + s]; redB[t] += redB[t + s]; }
        __syncthreads();
    }
    if (t == 0) {
        float Sx2 = 0.f;
        for (int g = 0; g < 16; ++g) Sx2 += ws[WS_SX2P + b * 16 + g];
        float inv = gamma[0] / (float)NN;
        ws[WS_ND2 + b] = Sx2 + 2.f * inv * redA[0] + inv * inv * redB[0];
        ws[WS_NX2 + b] = Sx2;
    }
}

// lip -> gamma_eff
__global__ void klip(const float* __restrict__ gamma, float* __restrict__ ws) {
    if (threadIdx.x == 0) {
        float d2 = 0.f, x2 = 0.f;
        for (int b = 0; b < NB; ++b) { d2 += ws[WS_ND2 + b]; x2 += ws[WS_NX2 + b]; }
        float lip = sqrtf(d2 / x2);
        float factor = (lip > 0.9f) ? (0.9f / lip) : 1.0f;
        ws[WS_GE] = gamma[0] * factor;
    }
}

// Output 0: 2x + (ge/N)(Sve[c] + ek[m]*Sv[c]), float4
__global__ void kout0(const float* __restrict__ x, const float* __restrict__ ws,
                      float* __restrict__ out) {
    int bid = blockIdx.x;            // 2048: b*256 + c
    int b = bid >> 8, c = bid & 255, t = threadIdx.x;  // 256
    const float* st = ws + WS_STAT + b * STAT_STRIDE;
    float ge = ws[WS_GE] * (1.f / (float)NN);
    float sv = st[ST_SV + c], sve = st[ST_SVE + c];
    float4 ek4 = ((const float4*)(st + ST_EK))[t];
    size_t i4 = (size_t)bid * 256 + t;
    float4 x4 = ((const float4*)x)[i4];
    float4 o;
    o.x = 2.f * x4.x + ge * (sve + ek4.x * sv);
    o.y = 2.f * x4.y + ge * (sve + ek4.y * sv);
    o.z = 2.f * x4.z + ge * (sve + ek4.z * sv);
    o.w = 2.f * x4.w + ge * (sve + ek4.w * sv);
    ((float4*)out)[i4] = o;
}

// Reduce Vs/Ve partials of u (v_0)
__global__ void kredu(const float* __restrict__ u, float* __restrict__ ws) {
    const int bid = blockIdx.x;      // 256: b*32 + ch
    const int b = bid >> 5, ch = bid & 31;
    const int t = threadIdx.x;       // 512
    const int col = t & 31, q = t >> 5;
    const int nb = ch * 32;
    __shared__ float ekc[32];
    __shared__ float VsPl[NC], VePl[NC];
    if (t < 32) ekc[t] = ws[WS_STAT + b * STAT_STRIDE + ST_EK + nb + t];
    __syncthreads();
    const float* ub = u + (size_t)b * NC * NN + nb + col;
    float ekv = ekc[col];
    for (int i = 0; i < 16; ++i) {
        int c = q * 16 + i;
        float uv = ub[(size_t)c * NN];
        float s1 = uv, s2 = uv * ekv;
        for (int off = 16; off > 0; off >>= 1) {
            s1 += __shfl_down(s1, off, 32);
            s2 += __shfl_down(s2, off, 32);
        }
        if (col == 0) { VsPl[c] = s1; VePl[c] = s2; }
    }
    __syncthreads();
    if (t < NC) {
        ws[WS_VSP + (size_t)(b * 32 + ch) * NC + t] = VsPl[t];
        ws[WS_VEP + (size_t)(b * 32 + ch) * NC + t] = VePl[t];
    }
}

// Finalize Vs/Ve -> p, r, sB; accumulate trace term
__global__ void ktiny(const float* __restrict__ Wv, const float* __restrict__ bv,
                      float* __restrict__ ws, float* __restrict__ out,
                      int j, float coef) {
    int b = blockIdx.x, t = threadIdx.x;  // 8 blocks x 256
    __shared__ float Vsl[NC], Vel[NC], red[NC];
    float vs = 0.f, ve = 0.f;
    for (int k = 0; k < 32; ++k) {
        vs += ws[WS_VSP + (size_t)(b * 32 + k) * NC + t];
        ve += ws[WS_VEP + (size_t)(b * 32 + k) * NC + t];
    }
    Vsl[t] = vs; Vel[t] = ve;
    __syncthreads();
    float pa = 0.f, ra = 0.f;
    for (int c = 0; c < NC; ++c) {
        float w = Wv[c * NC + t];
        pa += w * Vsl[c];
        ra += w * Vel[c];
    }
    float s = ws[WS_GE] * (1.f / (float)NN);
    ws[WS_P + b * NC + t] = s * pa;
    ws[WS_R + b * NC + t] = s * ra;
    red[t] = bv[t] * Vsl[t];
    __syncthreads();
    for (int sh = 128; sh > 0; sh >>= 1) { if (t < sh) red[t] += red[t + sh]; __syncthreads(); }
    if (t == 0) {
        ws[WS_SB + b] = s * red[0];
        if (j == 0) {
            ws[WS_TR + b] = 0.f;
        } else {
            float dot = 0.f;
            for (int k = 0; k < 32; ++k) dot += ws[WS_DOTP + b * 32 + k];
            float trv = ws[WS_TR + b] + coef * dot;
            ws[WS_TR + b] = trv;
            if (j == 5) out[2097152 + b] = trv;
        }
    }
}

// One vjp application + fused next reductions + trace dot
__global__ void kupd(const float* __restrict__ x, const float* __restrict__ u,
                     float* __restrict__ ws, const float* __restrict__ src,
                     float* __restrict__ dst) {
    const int bid = blockIdx.x;      // 256: b*32 + ch
    const int b = bid >> 5, ch = bid & 31;
    const int t = threadIdx.x;       // 512
    const int col = t & 31, q = t >> 5;
    const int nb = ch * 32;
    __shared__ float pl[NC], rl[NC], aql[NC], akl[NC], Svl[NC];
    __shared__ float redA[512], redB[512];
    __shared__ float tl[32], pzl[32];
    __shared__ float VsPl[NC], VePl[NC];
    const float* st = ws + WS_STAT + b * STAT_STRIDE;
    if (t < NC) {
        pl[t]  = ws[WS_P + b * NC + t];
        rl[t]  = ws[WS_R + b * NC + t];
        aql[t] = ws[WS_AQ + t];
        akl[t] = ws[WS_AK + t];
        Svl[t] = st[ST_SV + t];
    }
    __syncthreads();
    const float sB = ws[WS_SB + b];
    const float sg = ws[WS_GE] * (1.f / (float)NN);
    const float* vb = src + (size_t)b * NC * NN + nb + col;
    const float* xb = x + (size_t)b * NC * NN + nb + col;
    float vreg[16];
    float ta = 0.f, pza = 0.f;
    for (int i = 0; i < 16; ++i) {
        int c = q * 16 + i;
        float vv = vb[(size_t)c * NN];
        vreg[i] = vv;
        ta += vv * Svl[c];
        pza += xb[(size_t)c * NN] * pl[c];
    }
    redA[t] = ta; redB[t] = pza;
    __syncthreads();
    if (t < 32) {
        float tv = 0.f, pv = 0.f;
        for (int qq = 0; qq < 16; ++qq) { tv += redA[qq * 32 + t]; pv += redB[qq * 32 + t]; }
        tl[t] = sg * tv;
        pzl[t] = pv;
    }
    __syncthreads();
    const float eqv = st[ST_EQ + nb + col];
    const float ekv = st[ST_EK + nb + col];
    const float tv  = tl[col];
    const float pzv = pzl[col] + sB;
    float* db = dst + (size_t)b * NC * NN + nb + col;
    const float* ub = u + (size_t)b * NC * NN + nb + col;
    float dot = 0.f;
    for (int i = 0; i < 16; ++i) {
        int c = q * 16 + i;
        float w = vreg[i] + pl[c] * eqv + aql[c] * pzv + akl[c] * tv + rl[c];
        db[(size_t)c * NN] = w;
        dot += w * ub[(size_t)c * NN];
        float s1 = w, s2 = w * ekv;
        for (int off = 16; off > 0; off >>= 1) {
            s1 += __shfl_down(s1, off, 32);
            s2 += __shfl_down(s2, off, 32);
        }
        if (col == 0) { VsPl[c] = s1; VePl[c] = s2; }
    }
    redA[t] = dot;
    __syncthreads();
    for (int sh = 256; sh > 0; sh >>= 1) { if (t < sh) redA[t] += redA[t + sh]; __syncthreads(); }
    if (t == 0) ws[WS_DOTP + b * 32 + ch] = redA[0];
    if (t < NC) {
        ws[WS_VSP + (size_t)(b * 32 + ch) * NC + t] = VsPl[t];
        ws[WS_VEP + (size_t)(b * 32 + ch) * NC + t] = VePl[t];
    }
}

extern "C" void kernel_launch(void* const* d_in, const int* in_sizes, int n_in,
                              void* d_out, int out_size, void* d_ws, size_t ws_size,
                              hipStream_t stream) {
    const float* x     = (const float*)d_in[0];
    const float* Wq    = (const float*)d_in[1];
    const float* bq    = (const float*)d_in[2];
    const float* Wk    = (const float*)d_in[3];
    const float* bk    = (const float*)d_in[4];
    const float* Wc    = (const float*)d_in[5];
    const float* Wv    = (const float*)d_in[6];
    const float* bv    = (const float*)d_in[7];
    const float* gamma = (const float*)d_in[8];
    const float* u     = (const float*)d_in[9];
    float* out = (float*)d_out;
    float* ws  = (float*)d_ws;
    float* V   = ws + WS_V;

    k1<<<dim3(128), dim3(256), 0, stream>>>(x, Wq, bq, Wk, bk, Wc, ws);
    k2<<<dim3(32), dim3(256), 0, stream>>>(ws);
    k3<<<dim3(128), dim3(256), 0, stream>>>(x, ws);
    k4<<<dim3(8), dim3(256), 0, stream>>>(Wv, bv, gamma, ws);
    klip<<<dim3(1), dim3(64), 0, stream>>>(gamma, ws);
    kout0<<<dim3(2048), dim3(256), 0, stream>>>(x, ws, out);
    kredu<<<dim3(256), dim3(512), 0, stream>>>(u, ws);

    const float coefs[6] = {0.f, 1.f, -0.5f, 1.f / 3.f, -0.25f, 0.2f};
    ktiny<<<dim3(NB), dim3(256), 0, stream>>>(Wv, bv, ws, out, 0, 0.f);
    for (int j = 1; j <= 5; ++j) {
        const float* src = (j == 1) ? u : (const float*)V;
        kupd<<<dim3(256), dim3(512), 0, stream>>>(x, u, ws, src, V);
        ktiny<<<dim3(NB), dim3(256), 0, stream>>>(Wv, bv, ws, out, j, coefs[j]);
    }
}

// Round 3
// 133.124 us; speedup vs baseline: 1.6682x; 1.4751x over previous
//
#include <hip/hip_runtime.h>
#include <math.h>

// Problem constants
#define NB 8      // batch
#define NC 256    // channels
#define NN 1024   // spatial H*W
#define NICH 64   // inter channels

// ws layout (float offsets)
#define WS_AQ    0        // [256]
#define WS_AK    256      // [256]
#define WS_CQ    512
#define WS_CK    513
#define WS_MOM   520      // [32][4]: Seq,Sek,Sek2,Sekq partials per (b,qchunk)
#define WS_SX    1024     // [8][256]
#define WS_XE    3072     // [8][256]
#define WS_XK    5120     // [8][256]
#define WS_SX2P  7168     // [128]
#define WS_UUP   7296     // [128]
#define WS_ND2   7424     // [8]
#define WS_NX2   7432     // [8]
#define WS_VSU   7680     // [8][256]  u·1
#define WS_UE    9728     // [8][256]  u·eq
#define WS_VEU   11776    // [8][256]  u·ek
#define WS_CAQ   13824    // [8][256]  x·(u^T aq)
#define WS_CAK   15872    // [8][256]  x·(u^T ak)
#define WS_CUAK  17920    // [8][256]  u·(u^T ak)
#define WS_STAT  20480    // [8] stride 2560: eq,ek,Sv,Sve
#define STAT_STRIDE 2560
#define ST_EQ    0        // [1024]
#define ST_EK    1024     // [1024]
#define ST_SV    2048     // [256]
#define ST_SVE   2304     // [256]
#define WS_MAQ   40960    // [8][1024]  u^T aq
#define WS_MAK   49152    // [8][1024]  u^T ak
#define WS_EQP   57344    // [128][1024]
#define WS_EKP   188416   // [128][1024] ends 319488 floats

// k1: per (b,16-ch group): eq/ek partials over n, exact sx per channel; aq/ak/cq/ck.
__global__ void k1(const float* __restrict__ x, const float* __restrict__ Wq,
                   const float* __restrict__ bq, const float* __restrict__ Wk,
                   const float* __restrict__ bk, const float* __restrict__ Wc,
                   float* __restrict__ ws) {
    const int bid = blockIdx.x;          // 128: b*16+g
    const int b = bid >> 4, g = bid & 15;
    const int t = threadIdx.x;           // 256
    const int c0 = g * 16;
    __shared__ float aql[16], akl[16];
    __shared__ float sxw[16][4];
    if (t < 16) {
        float a = 0.f, k = 0.f;
        for (int o = 0; o < NICH; ++o) {
            a += Wc[o] * Wq[o * NC + c0 + t];
            k += Wc[NICH + o] * Wk[o * NC + c0 + t];
        }
        aql[t] = a; akl[t] = k;
        ws[WS_AQ + c0 + t] = a;
        ws[WS_AK + c0 + t] = k;
    }
    if (t == 16) { float s = 0.f; for (int o = 0; o < 64; ++o) s += Wc[o] * bq[o]; ws[WS_CQ] = s; }
    if (t == 17) { float s = 0.f; for (int o = 0; o < 64; ++o) s += Wc[NICH + o] * bk[o]; ws[WS_CK] = s; }
    __syncthreads();
    const float* xb = x + ((size_t)b * NC + c0) * NN;
    float eqp0 = 0.f, eqp1 = 0.f, eqp2 = 0.f, eqp3 = 0.f;
    float ekp0 = 0.f, ekp1 = 0.f, ekp2 = 0.f, ekp3 = 0.f;
    const int wid = t >> 6, lane = t & 63;
    for (int c = 0; c < 16; ++c) {
        float x0 = xb[c * NN + t];
        float x1 = xb[c * NN + t + 256];
        float x2 = xb[c * NN + t + 512];
        float x3 = xb[c * NN + t + 768];
        float a = aql[c], k = akl[c];
        eqp0 += a * x0; eqp1 += a * x1; eqp2 += a * x2; eqp3 += a * x3;
        ekp0 += k * x0; ekp1 += k * x1; ekp2 += k * x2; ekp3 += k * x3;
        float s = x0 + x1 + x2 + x3;
        for (int off = 32; off > 0; off >>= 1) s += __shfl_down(s, off, 64);
        if (lane == 0) sxw[c][wid] = s;
    }
    __syncthreads();
    if (t < 16) ws[WS_SX + b * NC + c0 + t] = sxw[t][0] + sxw[t][1] + sxw[t][2] + sxw[t][3];
    size_t pb = (size_t)bid * 1024;
    ws[WS_EQP + pb + t]       = eqp0;
    ws[WS_EQP + pb + t + 256] = eqp1;
    ws[WS_EQP + pb + t + 512] = eqp2;
    ws[WS_EQP + pb + t + 768] = eqp3;
    ws[WS_EKP + pb + t]       = ekp0;
    ws[WS_EKP + pb + t + 256] = ekp1;
    ws[WS_EKP + pb + t + 512] = ekp2;
    ws[WS_EKP + pb + t + 768] = ekp3;
}

// ku1: column dots of u: mu_aq = u^T aq, mu_ak = u^T ak (needs only k1)
__global__ void ku1(const float* __restrict__ u, float* __restrict__ ws) {
    const int bid = blockIdx.x;      // 32: b*4+q
    const int b = bid >> 2, q = bid & 3;
    const int t = threadIdx.x;       // 256
    __shared__ float aql[NC], akl[NC];
    aql[t] = ws[WS_AQ + t];
    akl[t] = ws[WS_AK + t];
    __syncthreads();
    const int n = q * 256 + t;
    const float* ub = u + (size_t)b * NC * NN + n;
    float maq = 0.f, mak = 0.f;
#pragma unroll 8
    for (int c = 0; c < NC; ++c) {
        float uv = ub[(size_t)c * NN];
        maq += aql[c] * uv;
        mak += akl[c] * uv;
    }
    ws[WS_MAQ + b * NN + n] = maq;
    ws[WS_MAK + b * NN + n] = mak;
}

// k2: finalize eq/ek, 4 moments (Seq, Sek, Sek2, Sekq)
__global__ void k2(float* __restrict__ ws) {
    const int bid = blockIdx.x;      // 32: b*4+qc
    const int b = bid >> 2, qc = bid & 3;
    const int t = threadIdx.x;       // 256
    const int n = qc * 256 + t;
    const float cq = ws[WS_CQ], ck = ws[WS_CK];
    float e = 0.f, k = 0.f;
    for (int g = 0; g < 16; ++g) {
        size_t pb = (size_t)(b * 16 + g) * 1024 + n;
        e += ws[WS_EQP + pb];
        k += ws[WS_EKP + pb];
    }
    e += cq; k += ck;
    float* st = ws + WS_STAT + b * STAT_STRIDE;
    st[ST_EQ + n] = e;
    st[ST_EK + n] = k;
    float d[4] = {e, k, k * k, e * k};
    __shared__ float dred[4][4];
    const int wid = t >> 6, lane = t & 63;
    for (int off = 32; off > 0; off >>= 1)
        for (int m = 0; m < 4; ++m) d[m] += __shfl_down(d[m], off, 64);
    if (lane == 0) for (int m = 0; m < 4; ++m) dred[m][wid] = d[m];
    __syncthreads();
    if (t == 0)
        for (int m = 0; m < 4; ++m)
            ws[WS_MOM + bid * 4 + m] = dred[m][0] + dred[m][1] + dred[m][2] + dred[m][3];
}

// k3: fused row-dots over x and u:
//  x: xe=x·eq, xk=x·ek, Sx2 | caq=x·mu_aq, cak=x·mu_ak
//  u: Vsu=u·1, Ue=u·eq, Veu=u·ek, uu | cuak=u·mu_ak
__global__ void k3(const float* __restrict__ x, const float* __restrict__ u,
                   float* __restrict__ ws) {
    const int bid = blockIdx.x;   // 128: b*16+g
    const int b = bid >> 4, g = bid & 15;
    const int t = threadIdx.x;    // 256
    const int c0 = g * 16;
    __shared__ float eql[NN], ekl[NN], maql[NN], makl[NN];
    __shared__ float wv8[16][8][4];
    __shared__ float accw[2][4];
    const float* st = ws + WS_STAT + b * STAT_STRIDE;
    for (int j = 0; j < 4; ++j) {
        int n = t + 256 * j;
        eql[n]  = st[ST_EQ + n];
        ekl[n]  = st[ST_EK + n];
        maql[n] = ws[WS_MAQ + b * NN + n];
        makl[n] = ws[WS_MAK + b * NN + n];
    }
    __syncthreads();
    const float* xb = x + ((size_t)b * NC + c0) * NN;
    const float* ub = u + ((size_t)b * NC + c0) * NN;
    float x2a = 0.f, uua = 0.f;
    const int wid = t >> 6, lane = t & 63;
    for (int c = 0; c < 16; ++c) {
        float d[8] = {0.f, 0.f, 0.f, 0.f, 0.f, 0.f, 0.f, 0.f};
        for (int j = 0; j < 4; ++j) {
            int n = t + 256 * j;
            float xv = xb[c * NN + n], uv = ub[c * NN + n];
            float e = eql[n], kk = ekl[n], ma = maql[n], mk = makl[n];
            d[0] += xv * e;   // xe
            d[1] += xv * kk;  // xk
            d[2] += uv;       // Vsu
            d[3] += uv * e;   // Ue
            d[4] += uv * kk;  // Veu
            d[5] += xv * ma;  // caq
            d[6] += xv * mk;  // cak
            d[7] += uv * mk;  // cuak
            x2a += xv * xv;
            uua += uv * uv;
        }
        for (int off = 32; off > 0; off >>= 1)
            for (int m = 0; m < 8; ++m) d[m] += __shfl_down(d[m], off, 64);
        if (lane == 0) for (int m = 0; m < 8; ++m) wv8[c][m][wid] = d[m];
    }
    for (int off = 32; off > 0; off >>= 1) {
        x2a += __shfl_down(x2a, off, 64);
        uua += __shfl_down(uua, off, 64);
    }
    if (lane == 0) { accw[0][wid] = x2a; accw[1][wid] = uua; }
    __syncthreads();
    if (t < 16) {
        int c = t;
        float v0 = wv8[c][0][0] + wv8[c][0][1] + wv8[c][0][2] + wv8[c][0][3];
        float v1 = wv8[c][1][0] + wv8[c][1][1] + wv8[c][1][2] + wv8[c][1][3];
        float v2 = wv8[c][2][0] + wv8[c][2][1] + wv8[c][2][2] + wv8[c][2][3];
        float v3 = wv8[c][3][0] + wv8[c][3][1] + wv8[c][3][2] + wv8[c][3][3];
        float v4 = wv8[c][4][0] + wv8[c][4][1] + wv8[c][4][2] + wv8[c][4][3];
        float v5 = wv8[c][5][0] + wv8[c][5][1] + wv8[c][5][2] + wv8[c][5][3];
        float v6 = wv8[c][6][0] + wv8[c][6][1] + wv8[c][6][2] + wv8[c][6][3];
        float v7 = wv8[c][7][0] + wv8[c][7][1] + wv8[c][7][2] + wv8[c][7][3];
        ws[WS_XE   + b * NC + c0 + c] = v0;
        ws[WS_XK   + b * NC + c0 + c] = v1;
        ws[WS_VSU  + b * NC + c0 + c] = v2;
        ws[WS_UE   + b * NC + c0 + c] = v3;
        ws[WS_VEU  + b * NC + c0 + c] = v4;
        ws[WS_CAQ  + b * NC + c0 + c] = v5;
        ws[WS_CAK  + b * NC + c0 + c] = v6;
        ws[WS_CUAK + b * NC + c0 + c] = v7;
    }
    if (t == 0) {
        ws[WS_SX2P + bid] = accw[0][0] + accw[0][1] + accw[0][2] + accw[0][3];
        ws[WS_UUP + bid]  = accw[1][0] + accw[1][1] + accw[1][2] + accw[1][3];
    }
}

// k4: Sv/Sve + algebraic lip-numerator d2 (no extra pass over x)
__global__ void k4(const float* __restrict__ Wv, const float* __restrict__ bv,
                   const float* __restrict__ gamma, float* __restrict__ ws) {
    const int b = blockIdx.x, t = threadIdx.x;  // 8 x 256
    __shared__ float sxl[NC], xel[NC];
    __shared__ float redA[256], redB[256];
    sxl[t] = ws[WS_SX + b * NC + t];
    xel[t] = ws[WS_XE + b * NC + t];
    __syncthreads();
    float Wsx = 0.f, Wxe = 0.f;
    const float* wr = Wv + (size_t)t * NC;
    for (int k = 0; k < NC; ++k) { float w = wr[k]; Wsx += w * sxl[k]; Wxe += w * xel[k]; }
    float Seq = 0.f, Sek = 0.f, Sek2 = 0.f;
    for (int q = 0; q < 4; ++q) {
        Seq  += ws[WS_MOM + (b * 4 + q) * 4 + 0];
        Sek  += ws[WS_MOM + (b * 4 + q) * 4 + 1];
        Sek2 += ws[WS_MOM + (b * 4 + q) * 4 + 2];
    }
    const float cq = ws[WS_CQ], ck = ws[WS_CK];
    float bvc = bv[t];
    float Sv  = Wsx + (float)NN * bvc;
    float SvL = Wsx;
    float Sve = Wxe + bvc * Seq;
    float A   = 2.f * Sve - bvc * Seq - cq * Sv;
    float* st = ws + WS_STAT + b * STAT_STRIDE;
    st[ST_SV + t] = Sv; st[ST_SVE + t] = Sve;
    float sx = sxl[t];
    float xk = ws[WS_XK + b * NC + t];
    float xkL = xk - ck * sx;
    float T1c = A * sx + Sv * xkL + SvL * xk;
    float SP  = Sek - (float)NN * ck;
    float SP2 = Sek2 - 2.f * ck * Sek + (float)NN * ck * ck;
    float SPQ = Sek2 - ck * Sek;
    float T2c = (float)NN * A * A + Sv * Sv * SP2 + SvL * SvL * Sek2
              + 2.f * A * Sv * SP + 2.f * A * SvL * Sek + 2.f * Sv * SvL * SPQ;
    redA[t] = T1c; redB[t] = T2c;
    __syncthreads();
    for (int s = 128; s > 0; s >>= 1) {
        if (t < s) { redA[t] += redA[t + s]; redB[t] += redB[t + s]; }
        __syncthreads();
    }
    if (t == 0) {
        float Sx2 = 0.f;
        for (int g = 0; g < 16; ++g) Sx2 += ws[WS_SX2P + b * 16 + g];
        float inv = gamma[0] / (float)NN;
        ws[WS_ND2 + b] = Sx2 + 2.f * inv * redA[0] + inv * inv * redB[0];
        ws[WS_NX2 + b] = Sx2;
    }
}

// kiter: the whole 5-term vjp/trace recursion, closed-form, per-batch block.
__global__ void kiter(const float* __restrict__ Wv, const float* __restrict__ bv,
                      const float* __restrict__ gamma, float* __restrict__ ws,
                      float* __restrict__ out) {
    const int b = blockIdx.x, t = threadIdx.x;  // 8 x 256
    const int wid = t >> 6, lane = t & 63;
    __shared__ float Svl[NC], sxl[NC], xkl[NC], caql[NC], cakl[NC], Uel[NC],
                     Vsul[NC], aql[NC], akl[NC], bvl[NC], Vs[NC], Ve[NC];
    __shared__ float dred[9][4];
    const float* st = ws + WS_STAT + b * STAT_STRIDE;
    Svl[t]  = st[ST_SV + t];
    sxl[t]  = ws[WS_SX  + b * NC + t];
    xkl[t]  = ws[WS_XK  + b * NC + t];
    caql[t] = ws[WS_CAQ + b * NC + t];
    cakl[t] = ws[WS_CAK + b * NC + t];
    Uel[t]  = ws[WS_UE  + b * NC + t];
    Vsul[t] = ws[WS_VSU + b * NC + t];
    aql[t]  = ws[WS_AQ + t];
    akl[t]  = ws[WS_AK + t];
    bvl[t]  = bv[t];
    float veu_t  = ws[WS_VEU  + b * NC + t];
    float cuak_t = ws[WS_CUAK + b * NC + t];
    Vs[t] = Vsul[t]; Ve[t] = veu_t;
    __syncthreads();
    // gamma_eff (redundant per thread; uniform loads)
    float ge;
    { float dd = 0.f, xx = 0.f;
      for (int bb = 0; bb < NB; ++bb) { dd += ws[WS_ND2 + bb]; xx += ws[WS_NX2 + bb]; }
      float lip = sqrtf(dd / xx);
      ge = gamma[0] * ((lip > 0.9f) ? (0.9f / lip) : 1.f); }
    const float s = ge * (1.f / (float)NN);
    float Seq = 0.f, Sek = 0.f, Sekq = 0.f;
    for (int q = 0; q < 4; ++q) {
        Seq  += ws[WS_MOM + (b * 4 + q) * 4 + 0];
        Sek  += ws[WS_MOM + (b * 4 + q) * 4 + 1];
        Sekq += ws[WS_MOM + (b * 4 + q) * 4 + 3];
    }
    float uu = 0.f;
    for (int g = 0; g < 16; ++g) uu += ws[WS_UUP + b * 16 + g];
    // prologue dots
    float pr[9];
    {
        float d[9];
        d[0] = Svl[t] * cuak_t;   // g2a = Sv·(u mu_ak) = ak^T uu^T Sv
        d[1] = aql[t] * Vsul[t];  // aq·Vsu
        d[2] = akl[t] * Vsul[t];  // ak·Vsu
        d[3] = akl[t] * Uel[t];   // ak·Ue
        d[4] = Svl[t] * Vsul[t];  // Sv·Vsu = S(tau_u)
        d[5] = Svl[t] * veu_t;    // Sv·Veu = tau_u·ek
        d[6] = Svl[t] * aql[t];   // Sv·aq
        d[7] = Svl[t] * akl[t];   // Sv·ak
        d[8] = 0.f;
        for (int off = 32; off > 0; off >>= 1)
            for (int m = 0; m < 9; ++m) d[m] += __shfl_down(d[m], off, 64);
        if (lane == 0) for (int m = 0; m < 9; ++m) dred[m][wid] = d[m];
        __syncthreads();
        for (int m = 0; m < 9; ++m) pr[m] = dred[m][0] + dred[m][1] + dred[m][2] + dred[m][3];
        __syncthreads();
    }
    const float g2a = pr[0], aqVsu = pr[1], akVsu = pr[2], akUe = pr[3],
                SvVsu = pr[4], SvVeu = pr[5], Svaq = pr[6], Svak = pr[7];
    const float lam = 1.f + s * Svak;
    float alpha = 1.f, beta = 0.f, gam = 0.f, delta[5] = {0.f, 0.f, 0.f, 0.f, 0.f};
    float sxPi[5], xkPi[5], cakPi[5];
    float dot = uu, tr = 0.f;
    const float coef[5] = {1.f, -0.5f, 1.f / 3.f, -0.25f, 0.2f};
    for (int j = 0; j < 5; ++j) {
        // P = s*Wv^T Vs ; R = s*Wv^T Ve   (one Wv sweep for both)
        float pa = 0.f, ra = 0.f;
        for (int c = 0; c < NC; ++c) {
            float w = Wv[c * NC + t];
            pa += w * Vs[c];
            ra += w * Ve[c];
        }
        float Pv = s * pa, Rv = s * ra;
        float d[9];
        d[0] = Svl[t] * Pv;   // Sv·P
        d[1] = Svl[t] * Rv;   // Sv·R
        d[2] = bvl[t] * Vs[t];// bv·Vs
        d[3] = sxl[t] * Pv;   // sx·P = S(pi)
        d[4] = xkl[t] * Pv;   // xk·P = ek·pi
        d[5] = caql[t] * Pv;  // aq·(u pi)
        d[6] = cakl[t] * Pv;  // ak·(u pi)
        d[7] = Uel[t] * Pv;   // Ue·P
        d[8] = Vsul[t] * Rv;  // Vsu·R
        for (int off = 32; off > 0; off >>= 1)
            for (int m = 0; m < 9; ++m) d[m] += __shfl_down(d[m], off, 64);
        if (lane == 0) for (int m = 0; m < 9; ++m) dred[m][wid] = d[m];
        __syncthreads();
        float sm[9];
        for (int m = 0; m < 9; ++m) sm[m] = dred[m][0] + dred[m][1] + dred[m][2] + dred[m][3];
        const float svP = sm[0], svR = sm[1], bvVs = sm[2], sxP = sm[3], xkP = sm[4],
                    caqP = sm[5], cakP = sm[6], ueP = sm[7], vsuR = sm[8];
        const float sB = s * bvVs;
        float St  = s * (alpha * SvVsu + beta * (float)NN + gam * Seq);
        float tek = s * (alpha * SvVeu + beta * Sek + gam * Sekq);
        float uta = s * (alpha * g2a + beta * akVsu + gam * akUe);
        for (int i = 0; i < j; ++i) {
            St  += s * delta[i] * sxPi[i];
            tek += s * delta[i] * xkPi[i];
            uta += s * delta[i] * cakPi[i];
        }
        dot += ueP + caqP + sB * aqVsu + uta + vsuR;
        tr  += coef[j] * dot;
        float nVs = Vs[t] + Pv * Seq + aql[t] * (sxP + (float)NN * sB) + akl[t] * St + Rv * (float)NN;
        float nVe = Ve[t] + Pv * Sekq + aql[t] * (xkP + sB * Sek) + akl[t] * tek + Rv * Sek;
        __syncthreads();   // everyone done reading Vs/Ve and dred
        Vs[t] = nVs; Ve[t] = nVe;
        float nbeta = lam * beta + Svaq * sB + svR;
        float ngam  = lam * gam + svP;
        for (int i = 0; i < j; ++i) delta[i] *= lam;
        delta[j] = Svaq;
        alpha *= lam; beta = nbeta; gam = ngam;
        sxPi[j] = sxP; xkPi[j] = xkP; cakPi[j] = cakP;
        __syncthreads();   // Vs/Ve visible for next matvec
    }
    if (t == 0) out[2097152 + b] = tr;
}

// Output 0: 2x + (ge/N)(Sve[c] + ek[m]*Sv[c]), float4; ge computed inline
__global__ void kout0(const float* __restrict__ x, const float* __restrict__ gamma,
                      const float* __restrict__ ws, float* __restrict__ out) {
    int bid = blockIdx.x;            // 2048: b*256 + c
    int b = bid >> 8, c = bid & 255, t = threadIdx.x;  // 256
    float dd = 0.f, xx = 0.f;
    for (int bb = 0; bb < NB; ++bb) { dd += ws[WS_ND2 + bb]; xx += ws[WS_NX2 + bb]; }
    float lip = sqrtf(dd / xx);
    float ge = gamma[0] * ((lip > 0.9f) ? (0.9f / lip) : 1.f) * (1.f / (float)NN);
    const float* st = ws + WS_STAT + b * STAT_STRIDE;
    float sv = st[ST_SV + c], sve = st[ST_SVE + c];
    float4 ek4 = ((const float4*)(st + ST_EK))[t];
    size_t i4 = (size_t)bid * 256 + t;
    float4 x4 = ((const float4*)x)[i4];
    float4 o;
    o.x = 2.f * x4.x + ge * (sve + ek4.x * sv);
    o.y = 2.f * x4.y + ge * (sve + ek4.y * sv);
    o.z = 2.f * x4.z + ge * (sve + ek4.z * sv);
    o.w = 2.f * x4.w + ge * (sve + ek4.w * sv);
    ((float4*)out)[i4] = o;
}

extern "C" void kernel_launch(void* const* d_in, const int* in_sizes, int n_in,
                              void* d_out, int out_size, void* d_ws, size_t ws_size,
                              hipStream_t stream) {
    const float* x     = (const float*)d_in[0];
    const float* Wq    = (const float*)d_in[1];
    const float* bq    = (const float*)d_in[2];
    const float* Wk    = (const float*)d_in[3];
    const float* bk    = (const float*)d_in[4];
    const float* Wc    = (const float*)d_in[5];
    const float* Wv    = (const float*)d_in[6];
    const float* bv    = (const float*)d_in[7];
    const float* gamma = (const float*)d_in[8];
    const float* u     = (const float*)d_in[9];
    float* out = (float*)d_out;
    float* ws  = (float*)d_ws;

    k1   <<<dim3(128),  dim3(256), 0, stream>>>(x, Wq, bq, Wk, bk, Wc, ws);
    ku1  <<<dim3(32),   dim3(256), 0, stream>>>(u, ws);
    k2   <<<dim3(32),   dim3(256), 0, stream>>>(ws);
    k3   <<<dim3(128),  dim3(256), 0, stream>>>(x, u, ws);
    k4   <<<dim3(8),    dim3(256), 0, stream>>>(Wv, bv, gamma, ws);
    kiter<<<dim3(8),    dim3(256), 0, stream>>>(Wv, bv, gamma, ws, out);
    kout0<<<dim3(2048), dim3(256), 0, stream>>>(x, gamma, ws, out);
}